// Round 1
// baseline (4051.232 us; speedup 1.0000x reference)
//
#include <hip/hip_runtime.h>
#include <hip/hip_bf16.h>

#define BATCH 64
#define SEQT  2048
#define FEAT  64
#define HID   128
#define G4    512   // 4*HID

// ---------- math helpers ----------
__device__ __forceinline__ float sigmoidf_(float x) {
    return 1.0f / (1.0f + __expf(-x));
}
__device__ __forceinline__ float seluf_(float x) {
    const float a = 1.6732632423543772f;
    const float s = 1.0507009873554805f;
    return x > 0.0f ? s * x : s * a * (__expf(x) - 1.0f);
}

// ---------- typed load/store helpers (fp32 or bf16 xz buffer) ----------
__device__ __forceinline__ float2 load2(const float* p) { return *(const float2*)p; }
__device__ __forceinline__ float2 load2(const __hip_bfloat16* p) {
    __hip_bfloat162 v = *(const __hip_bfloat162*)p;
    return make_float2(__low2float(v), __high2float(v));
}
__device__ __forceinline__ void store4(float* p, float a, float b, float c, float d) {
    *(float4*)p = make_float4(a, b, c, d);
}
__device__ __forceinline__ void store4(__hip_bfloat16* p, float a, float b, float c, float d) {
    p[0] = __float2bfloat16(a); p[1] = __float2bfloat16(b);
    p[2] = __float2bfloat16(c); p[3] = __float2bfloat16(d);
}

// ---------- input-projection GEMM: out[BT,512] = X[BT,K] @ W[K,512] + bias ----------
// grid = (BT/32, 4), block = 256. Tiles: 32 rows x 128 cols, K in chunks of 64.
template <typename OT>
__global__ __launch_bounds__(256) void gemm_xw_bias(
        const float* __restrict__ X, const float* __restrict__ W,
        const float* __restrict__ bias, OT* __restrict__ out, int K) {
    __shared__ float Ws[64 * 128];
    __shared__ float Xs[32 * 64];
    const int tid = threadIdx.x;
    const int r0  = blockIdx.x * 32;
    const int c0  = blockIdx.y * 128;
    const int tx  = tid & 31;    // 32 col-groups of 4 cols
    const int ty  = tid >> 5;    // 8 row-groups of 4 rows

    float acc[4][4];
#pragma unroll
    for (int i = 0; i < 4; ++i)
#pragma unroll
        for (int j = 0; j < 4; ++j) acc[i][j] = bias[c0 + tx * 4 + j];

    const int nkc = K >> 6;
    for (int kc = 0; kc < nkc; ++kc) {
        for (int idx = tid; idx < 64 * 128; idx += 256) {
            int k = idx >> 7, j = idx & 127;
            Ws[idx] = W[(size_t)(kc * 64 + k) * G4 + c0 + j];
        }
        for (int idx = tid; idx < 32 * 64; idx += 256) {
            int r = idx >> 6, k = idx & 63;
            Xs[idx] = X[(size_t)(r0 + r) * K + kc * 64 + k];
        }
        __syncthreads();
#pragma unroll 4
        for (int k = 0; k < 64; ++k) {
            float4 w = *(const float4*)&Ws[k * 128 + tx * 4];
#pragma unroll
            for (int i = 0; i < 4; ++i) {
                float xv = Xs[(ty * 4 + i) * 64 + k];
                acc[i][0] += xv * w.x; acc[i][1] += xv * w.y;
                acc[i][2] += xv * w.z; acc[i][3] += xv * w.w;
            }
        }
        __syncthreads();
    }
#pragma unroll
    for (int i = 0; i < 4; ++i) {
        store4(&out[(size_t)(r0 + ty * 4 + i) * G4 + c0 + tx * 4],
               acc[i][0], acc[i][1], acc[i][2], acc[i][3]);
    }
}

// ---------- recurrent LSTM layer ----------
// One block per batch row. 512 threads = 8 waves.
// waves 0..3: K in [0,64), waves 4..7: K in [64,128).
// Thread owns outputs j0, j0+1 where j0 = (wave&3)*128 + lane*2  -> U cols in 128 VGPRs.
template <typename XT>
__global__ __launch_bounds__(512, 2) void lstm_rec(
        const XT* __restrict__ xz, const float* __restrict__ U,
        float* __restrict__ hout) {
    const int b    = blockIdx.x;
    const int tid  = threadIdx.x;
    const int wave = tid >> 6;
    const int lane = tid & 63;
    const int half = wave >> 2;                  // K half
    const int j0   = (wave & 3) * 128 + lane * 2;

    __shared__ float h_lds[HID];
    __shared__ float part[2][G4];

    // Stage my two U columns (my K-half) into registers. Fully unrolled -> VGPRs.
    float uc0[64], uc1[64];
    {
        const float* Ub = U + (size_t)(half * 64) * G4 + j0;
#pragma unroll
        for (int k = 0; k < 64; ++k) {
            uc0[k] = Ub[(size_t)k * G4];
            uc1[k] = Ub[(size_t)k * G4 + 1];
        }
    }

    float c = 0.0f;
    if (tid < HID) h_lds[tid] = 0.0f;
    __syncthreads();

    const XT* xrow = xz + (size_t)b * SEQT * G4;
    float2 xv = make_float2(0.0f, 0.0f);
    if (half == 0) xv = load2(&xrow[j0]);        // t = 0 prefetch

    for (int t = 0; t < SEQT; ++t) {
        // prefetch next step's xz (in flight during the FMA phase)
        float2 nxv = make_float2(0.0f, 0.0f);
        if (half == 0 && t + 1 < SEQT) nxv = load2(&xrow[(size_t)(t + 1) * G4 + j0]);

        float a0 = (half == 0) ? xv.x : 0.0f;
        float a1 = (half == 0) ? xv.y : 0.0f;
        const float* hb = &h_lds[half * 64];
#pragma unroll
        for (int kk = 0; kk < 16; ++kk) {
            float4 hv = *(const float4*)&hb[kk * 4];
            a0 += hv.x * uc0[kk * 4 + 0]; a1 += hv.x * uc1[kk * 4 + 0];
            a0 += hv.y * uc0[kk * 4 + 1]; a1 += hv.y * uc1[kk * 4 + 1];
            a0 += hv.z * uc0[kk * 4 + 2]; a1 += hv.z * uc1[kk * 4 + 2];
            a0 += hv.w * uc0[kk * 4 + 3]; a1 += hv.w * uc1[kk * 4 + 3];
        }
        *(float2*)&part[half][j0] = make_float2(a0, a1);
        __syncthreads();

        if (tid < HID) {
            float zi = part[0][tid]       + part[1][tid];
            float zf = part[0][tid + 128] + part[1][tid + 128];
            float zg = part[0][tid + 256] + part[1][tid + 256];
            float zo = part[0][tid + 384] + part[1][tid + 384];
            float ig = sigmoidf_(zi);
            float fg = sigmoidf_(zf);
            float gg = seluf_(zg);
            float og = sigmoidf_(zo);
            c = fg * c + ig * gg;
            float h = og * seluf_(c);
            h_lds[tid] = h;
            hout[((size_t)b * SEQT + t) * HID + tid] = h;
        }
        __syncthreads();
        xv = nxv;
    }
}

// ---------- host launch ----------
extern "C" void kernel_launch(void* const* d_in, const int* in_sizes, int n_in,
                              void* d_out, int out_size, void* d_ws, size_t ws_size,
                              hipStream_t stream) {
    const float* x  = (const float*)d_in[0];
    const float* W1 = (const float*)d_in[1];
    const float* U1 = (const float*)d_in[2];
    const float* b1 = (const float*)d_in[3];
    const float* W2 = (const float*)d_in[4];
    const float* U2 = (const float*)d_in[5];
    const float* b2 = (const float*)d_in[6];
    float* out = (float*)d_out;

    const size_t BT = (size_t)BATCH * SEQT;
    const size_t xz_f32_bytes  = BT * G4 * sizeof(float);            // 256 MB
    const size_t xz_bf16_bytes = BT * G4 * sizeof(__hip_bfloat16);   // 128 MB
    const size_t h1_bytes      = BT * HID * sizeof(float);           // 64 MB

    dim3 ggrid((unsigned)(BT / 32), 4), gblk(256);
    dim3 rgrid(BATCH), rblk(512);

    if (ws_size >= xz_f32_bytes + h1_bytes) {
        // fp32 xz path (preferred)
        float* xz = (float*)d_ws;
        float* h1 = (float*)((char*)d_ws + xz_f32_bytes);
        gemm_xw_bias<float><<<ggrid, gblk, 0, stream>>>(x, W1, b1, xz, FEAT);
        lstm_rec<float><<<rgrid, rblk, 0, stream>>>(xz, U1, h1);
        gemm_xw_bias<float><<<ggrid, gblk, 0, stream>>>(h1, W2, b2, xz, HID);
        lstm_rec<float><<<rgrid, rblk, 0, stream>>>(xz, U2, out);
    } else {
        // bf16 xz fallback (192 MB workspace)
        __hip_bfloat16* xz = (__hip_bfloat16*)d_ws;
        float* h1 = (float*)((char*)d_ws + xz_bf16_bytes);
        gemm_xw_bias<__hip_bfloat16><<<ggrid, gblk, 0, stream>>>(x, W1, b1, xz, FEAT);
        lstm_rec<__hip_bfloat16><<<rgrid, rblk, 0, stream>>>(xz, U1, h1);
        gemm_xw_bias<__hip_bfloat16><<<ggrid, gblk, 0, stream>>>(h1, W2, b2, xz, HID);
        lstm_rec<__hip_bfloat16><<<rgrid, rblk, 0, stream>>>(xz, U2, out);
    }
}